// Round 1
// baseline (429.456 us; speedup 1.0000x reference)
//
#include <hip/hip_runtime.h>

#define NB 4
#define NC 64
#define NCH 32
#define NPIX 131072   // 32*64*64

// workspace float offsets
#define O_SUME 0                  // [NB]      sum of exp(relu(qr))
#define O_CTX  8                  // [NB][NCH] sum relu(vr)*e
#define O_QL   (8 + NB*NCH)       // 136 [NB][NCH] sum relu(ql)
#define O_SCA  (O_QL + NB*NCH)    // 264 [NB]  sum of channel_attn
#define O_SA   272                // [NB][NC]  spatial_attn
#define O_AVGX (O_SA + NB*NC)     // 528 [NB][NCH]
#define O_K    (O_AVGX + NB*NCH)  // 656 [NB][NC]

__device__ __forceinline__ float wave_sum64(float v) {
#pragma unroll
    for (int m = 32; m; m >>= 1) v += __shfl_xor(v, m, 64);
    return v;
}

// ---------------- Pass 1: qr / vr / ql reductions ----------------
__global__ __launch_bounds__(256) void k_pass1(
    const float* __restrict__ x, const float* __restrict__ wqr,
    const float* __restrict__ wvr, const float* __restrict__ wql,
    float* __restrict__ ws) {
    const int b = blockIdx.y;
    const float* xb = x + (size_t)b * NC * NPIX;
    __shared__ float red[1 + 2 * NCH];
    for (int i = threadIdx.x; i < 1 + 2 * NCH; i += 256) red[i] = 0.f;
    __syncthreads();

    float acc_e = 0.f;
    float acc_ctx[NCH], acc_ql[NCH];
#pragma unroll
    for (int i = 0; i < NCH; ++i) { acc_ctx[i] = 0.f; acc_ql[i] = 0.f; }

    const int PIX = 4;
    const int n_base = blockIdx.x * (256 * PIX) + threadIdx.x;
    for (int p = 0; p < PIX; ++p) {
        const int n = n_base + p * 256;
        float dv[NCH], dq[NCH], dqr = 0.f;
#pragma unroll
        for (int i = 0; i < NCH; ++i) { dv[i] = 0.f; dq[i] = 0.f; }
        for (int c4 = 0; c4 < NC; c4 += 4) {
            float xv0 = xb[(size_t)(c4 + 0) * NPIX + n];
            float xv1 = xb[(size_t)(c4 + 1) * NPIX + n];
            float xv2 = xb[(size_t)(c4 + 2) * NPIX + n];
            float xv3 = xb[(size_t)(c4 + 3) * NPIX + n];
            dqr = fmaf(wqr[c4 + 0], xv0, dqr);
            dqr = fmaf(wqr[c4 + 1], xv1, dqr);
            dqr = fmaf(wqr[c4 + 2], xv2, dqr);
            dqr = fmaf(wqr[c4 + 3], xv3, dqr);
#pragma unroll
            for (int ch = 0; ch < NCH; ++ch) {
                dv[ch] = fmaf(wvr[ch * NC + c4 + 0], xv0, dv[ch]);
                dv[ch] = fmaf(wvr[ch * NC + c4 + 1], xv1, dv[ch]);
                dv[ch] = fmaf(wvr[ch * NC + c4 + 2], xv2, dv[ch]);
                dv[ch] = fmaf(wvr[ch * NC + c4 + 3], xv3, dv[ch]);
                dq[ch] = fmaf(wql[ch * NC + c4 + 0], xv0, dq[ch]);
                dq[ch] = fmaf(wql[ch * NC + c4 + 1], xv1, dq[ch]);
                dq[ch] = fmaf(wql[ch * NC + c4 + 2], xv2, dq[ch]);
                dq[ch] = fmaf(wql[ch * NC + c4 + 3], xv3, dq[ch]);
            }
        }
        float e = __expf(fmaxf(dqr, 0.f));
        acc_e += e;
#pragma unroll
        for (int ch = 0; ch < NCH; ++ch) {
            acc_ctx[ch] += fmaxf(dv[ch], 0.f) * e;
            acc_ql[ch]  += fmaxf(dq[ch], 0.f);
        }
    }

    acc_e = wave_sum64(acc_e);
    if ((threadIdx.x & 63) == 0) atomicAdd(&red[0], acc_e);
#pragma unroll
    for (int ch = 0; ch < NCH; ++ch) {
        float v = wave_sum64(acc_ctx[ch]);
        float q = wave_sum64(acc_ql[ch]);
        if ((threadIdx.x & 63) == 0) {
            atomicAdd(&red[1 + ch], v);
            atomicAdd(&red[1 + NCH + ch], q);
        }
    }
    __syncthreads();
    if (threadIdx.x == 0) atomicAdd(&ws[O_SUME + b], red[0]);
    if (threadIdx.x < NCH) {
        atomicAdd(&ws[O_CTX + b * NCH + threadIdx.x], red[1 + threadIdx.x]);
        atomicAdd(&ws[O_QL  + b * NCH + threadIdx.x], red[1 + NCH + threadIdx.x]);
    }
}

// ---------------- Pass 2: context -> LN -> spatial_attn; avg_x ----------------
__global__ __launch_bounds__(256) void k_pass2(
    const float* __restrict__ wup, float* __restrict__ ws) {
    const int b = threadIdx.x >> 6;
    const int lane = threadIdx.x & 63;
    __shared__ float ln_s[NB][NCH];

    float se = ws[O_SUME + b];
    float ctx = (lane < NCH) ? (ws[O_CTX + b * NCH + lane] / se) : 0.f;
    float v = ctx, v2 = ctx * ctx;
#pragma unroll
    for (int m = 16; m; m >>= 1) {
        v  += __shfl_xor(v, m, 64);
        v2 += __shfl_xor(v2, m, 64);
    }
    float mu = v / (float)NCH;
    float var = v2 / (float)NCH - mu * mu;
    float lnv = (ctx - mu) * rsqrtf(var + 1e-5f);
    if (lane < NCH) ln_s[b][lane] = lnv;
    __syncthreads();

    float s = 0.f;
#pragma unroll
    for (int ch = 0; ch < NCH; ++ch) s = fmaf(wup[lane * NCH + ch], ln_s[b][ch], s);
    float sa = fminf(fmaxf((s + 3.f) * (1.f / 6.f), 0.f), 1.f);
    ws[O_SA + b * NC + lane] = sa;

    if (lane < NCH) {
        float l = ws[O_QL + b * NCH + lane] * (1.f / (float)NPIX);
        float mx = l;
#pragma unroll
        for (int m = 16; m; m >>= 1) mx = fmaxf(mx, __shfl_xor(mx, m, 64));
        float e = __expf(l - mx);
        float sm = e;
#pragma unroll
        for (int m = 16; m; m >>= 1) sm += __shfl_xor(sm, m, 64);
        ws[O_AVGX + b * NCH + lane] = e / sm;
    }
}

// ---------------- Pass 3: S_ca = sum_n sigmoid(avg_x . relu(wvl x)) ----------------
__global__ __launch_bounds__(256) void k_pass3(
    const float* __restrict__ x, const float* __restrict__ wvl,
    float* __restrict__ ws) {
    const int b = blockIdx.y;
    const float* xb = x + (size_t)b * NC * NPIX;
    __shared__ float red;
    if (threadIdx.x == 0) red = 0.f;
    __syncthreads();

    float acc = 0.f;
    const int PIX = 4;
    int n = blockIdx.x * (256 * PIX) + threadIdx.x;
    for (int p = 0; p < PIX; ++p, n += 256) {
        float dv[NCH];
#pragma unroll
        for (int i = 0; i < NCH; ++i) dv[i] = 0.f;
        for (int c4 = 0; c4 < NC; c4 += 4) {
            float xv0 = xb[(size_t)(c4 + 0) * NPIX + n];
            float xv1 = xb[(size_t)(c4 + 1) * NPIX + n];
            float xv2 = xb[(size_t)(c4 + 2) * NPIX + n];
            float xv3 = xb[(size_t)(c4 + 3) * NPIX + n];
#pragma unroll
            for (int ch = 0; ch < NCH; ++ch) {
                dv[ch] = fmaf(wvl[ch * NC + c4 + 0], xv0, dv[ch]);
                dv[ch] = fmaf(wvl[ch * NC + c4 + 1], xv1, dv[ch]);
                dv[ch] = fmaf(wvl[ch * NC + c4 + 2], xv2, dv[ch]);
                dv[ch] = fmaf(wvl[ch * NC + c4 + 3], xv3, dv[ch]);
            }
        }
        float s = 0.f;
#pragma unroll
        for (int ch = 0; ch < NCH; ++ch)
            s = fmaf(ws[O_AVGX + b * NCH + ch], fmaxf(dv[ch], 0.f), s);
        acc += 1.f / (1.f + __expf(-s));
    }
    acc = wave_sum64(acc);
    if ((threadIdx.x & 63) == 0) atomicAdd(&red, acc);
    __syncthreads();
    if (threadIdx.x == 0) atomicAdd(&ws[O_SCA + b], red);
}

// ---------------- Pass 4: SK gating -> K[b,c] ----------------
__global__ __launch_bounds__(256) void k_pass4(
    const float* __restrict__ wsk1, const float* __restrict__ wsk2,
    float* __restrict__ ws) {
    const int b = threadIdx.x >> 6;
    const int lane = threadIdx.x & 63;
    __shared__ float u_s[NB][NC];
    __shared__ float a1_s[NB][NCH];

    float sca = ws[O_SCA + b];
    float sa = ws[O_SA + b * NC + lane];
    float invn = 1.f / (float)NPIX;
    u_s[b][lane] = fmaf(sa, sca * invn, invn);
    __syncthreads();
    if (lane < NCH) {
        float s = 0.f;
#pragma unroll
        for (int c = 0; c < NC; ++c) s = fmaf(wsk1[lane * NC + c], u_s[b][c], s);
        a1_s[b][lane] = fmaxf(s, 0.f);
    }
    __syncthreads();
    float s2 = 0.f;
#pragma unroll
    for (int ch = 0; ch < NCH; ++ch) s2 = fmaf(wsk2[lane * NCH + ch], a1_s[b][ch], s2);
    s2 = fmaxf(s2, 0.f);
    float mx = s2;
#pragma unroll
    for (int m = 32; m; m >>= 1) mx = fmaxf(mx, __shfl_xor(mx, m, 64));
    float e = __expf(s2 - mx);
    float sm = e;
#pragma unroll
    for (int m = 32; m; m >>= 1) sm += __shfl_xor(sm, m, 64);
    float a = e / sm;
    ws[O_K + b * NC + lane] = fmaf(a, sa * sca, 1.f - a);
}

// ---------------- Pass 5: out = K[b,c] + relu(wres x) ----------------
__global__ __launch_bounds__(256) void k_pass5(
    const float* __restrict__ x, const float* __restrict__ wres,
    const float* __restrict__ ws, float* __restrict__ out) {
    const int b = blockIdx.y;
    const float* xb = x + (size_t)b * NC * NPIX;
    float* ob = out + (size_t)b * NC * NPIX;
    const int n = blockIdx.x * 256 + threadIdx.x;

    float acc[NC];
#pragma unroll
    for (int o = 0; o < NC; ++o) acc[o] = 0.f;
    for (int c4 = 0; c4 < NC; c4 += 4) {
        float xv0 = xb[(size_t)(c4 + 0) * NPIX + n];
        float xv1 = xb[(size_t)(c4 + 1) * NPIX + n];
        float xv2 = xb[(size_t)(c4 + 2) * NPIX + n];
        float xv3 = xb[(size_t)(c4 + 3) * NPIX + n];
#pragma unroll
        for (int o = 0; o < NC; ++o) {
            acc[o] = fmaf(wres[o * NC + c4 + 0], xv0, acc[o]);
            acc[o] = fmaf(wres[o * NC + c4 + 1], xv1, acc[o]);
            acc[o] = fmaf(wres[o * NC + c4 + 2], xv2, acc[o]);
            acc[o] = fmaf(wres[o * NC + c4 + 3], xv3, acc[o]);
        }
    }
#pragma unroll
    for (int o = 0; o < NC; ++o)
        ob[(size_t)o * NPIX + n] = ws[O_K + b * NC + o] + fmaxf(acc[o], 0.f);
}

extern "C" void kernel_launch(void* const* d_in, const int* in_sizes, int n_in,
                              void* d_out, int out_size, void* d_ws, size_t ws_size,
                              hipStream_t stream) {
    const float* x    = (const float*)d_in[0];
    const float* wqr  = (const float*)d_in[1];
    const float* wvr  = (const float*)d_in[2];
    const float* wup  = (const float*)d_in[3];
    const float* wql  = (const float*)d_in[4];
    const float* wvl  = (const float*)d_in[5];
    const float* wsk1 = (const float*)d_in[6];
    const float* wsk2 = (const float*)d_in[7];
    const float* wres = (const float*)d_in[8];
    float* out = (float*)d_out;
    float* ws  = (float*)d_ws;

    // zero the accumulator region (offsets 0 .. 272 floats)
    hipMemsetAsync(d_ws, 0, 272 * sizeof(float), stream);

    dim3 blk(256);
    dim3 g1(NPIX / (256 * 4), NB);   // 128 x 4
    k_pass1<<<g1, blk, 0, stream>>>(x, wqr, wvr, wql, ws);
    k_pass2<<<dim3(1), blk, 0, stream>>>(wup, ws);
    k_pass3<<<g1, blk, 0, stream>>>(x, wvl, ws);
    k_pass4<<<dim3(1), blk, 0, stream>>>(wsk1, wsk2, ws);
    dim3 g5(NPIX / 256, NB);         // 512 x 4
    k_pass5<<<g5, blk, 0, stream>>>(x, wres, ws, out);
}

// Round 2
// 252.571 us; speedup vs baseline: 1.7003x; 1.7003x over previous
//
#include <hip/hip_runtime.h>

#define NB 4
#define NC 64
#define NCH 32
#define NPIX 131072   // 32*64*64

// workspace float offsets
#define O_SUME 0                  // [NB]      sum of exp(relu(qr))
#define O_CTX  8                  // [NB][NCH] sum relu(vr)*e
#define O_QL   136                // [NB][NCH] sum relu(ql)
#define O_SCA  264                // [NB]      sum of channel_attn
#define O_SA   272                // [NB][NC]  spatial_attn
#define O_AVGX 528                // [NB][NCH]
#define O_K    656                // [NB][NC]
// transposed weights (c-major rows, contiguous outputs per c)
#define O_WT1  1024               // [64][80]: col0=wqr, 1..32=wvr, 33..64=wql
#define WT1_S  80
#define O_WT3  6144               // [64][32]: wvl
#define O_WT5  8192               // [64][64]: wres

__device__ __forceinline__ float wave_sum64(float v) {
#pragma unroll
    for (int m = 32; m; m >>= 1) v += __shfl_xor(v, m, 64);
    return v;
}

// ---------------- Prep: transpose weights into c-major layout ----------------
__global__ __launch_bounds__(256) void k_prep(
    const float* __restrict__ wqr, const float* __restrict__ wvr,
    const float* __restrict__ wql, const float* __restrict__ wvl,
    const float* __restrict__ wres, float* __restrict__ ws) {
    for (int i = threadIdx.x; i < NC * WT1_S; i += 256) {
        int c = i / WT1_S, j = i % WT1_S;
        float v = 0.f;
        if (j == 0)       v = wqr[c];
        else if (j <= 32) v = wvr[(j - 1) * NC + c];
        else if (j <= 64) v = wql[(j - 33) * NC + c];
        ws[O_WT1 + i] = v;
    }
    for (int i = threadIdx.x; i < NC * NCH; i += 256) {
        int c = i / NCH, ch = i % NCH;
        ws[O_WT3 + i] = wvl[ch * NC + c];
    }
    for (int i = threadIdx.x; i < NC * NC; i += 256) {
        int c = i / NC, o = i % NC;
        ws[O_WT5 + i] = wres[o * NC + c];
    }
}

// ---------------- Pass 1: qr / vr / ql reductions (1 pixel/thread) ----------------
__global__ __launch_bounds__(256) void k_pass1(
    const float* __restrict__ x, float* ws) {
    const int b = blockIdx.y;
    const float* xb = x + (size_t)b * NC * NPIX;
    const float* wt = ws + O_WT1;
    __shared__ float red[1 + 2 * NCH];
    for (int i = threadIdx.x; i < 1 + 2 * NCH; i += 256) red[i] = 0.f;
    __syncthreads();

    const int n = blockIdx.x * 256 + threadIdx.x;
    float dqr = 0.f;
    float dv[NCH], dq[NCH];
#pragma unroll
    for (int i = 0; i < NCH; ++i) { dv[i] = 0.f; dq[i] = 0.f; }

    for (int c = 0; c < NC; ++c) {
        const float xv = xb[(size_t)c * NPIX + n];
        const float* wr = wt + c * WT1_S;
        dqr = fmaf(wr[0], xv, dqr);
#pragma unroll
        for (int ch = 0; ch < NCH; ++ch) {
            dv[ch] = fmaf(wr[1 + ch], xv, dv[ch]);
            dq[ch] = fmaf(wr[33 + ch], xv, dq[ch]);
        }
    }

    const float e = __expf(fmaxf(dqr, 0.f));
    float acc_e = wave_sum64(e);
    if ((threadIdx.x & 63) == 0) atomicAdd(&red[0], acc_e);
#pragma unroll
    for (int ch = 0; ch < NCH; ++ch) {
        float v = wave_sum64(fmaxf(dv[ch], 0.f) * e);
        float q = wave_sum64(fmaxf(dq[ch], 0.f));
        if ((threadIdx.x & 63) == 0) {
            atomicAdd(&red[1 + ch], v);
            atomicAdd(&red[1 + NCH + ch], q);
        }
    }
    __syncthreads();
    if (threadIdx.x == 0) atomicAdd(&ws[O_SUME + b], red[0]);
    if (threadIdx.x < NCH) {
        atomicAdd(&ws[O_CTX + b * NCH + threadIdx.x], red[1 + threadIdx.x]);
        atomicAdd(&ws[O_QL  + b * NCH + threadIdx.x], red[1 + NCH + threadIdx.x]);
    }
}

// ---------------- Pass 2: context -> LN -> spatial_attn; avg_x ----------------
__global__ __launch_bounds__(256) void k_pass2(
    const float* __restrict__ wup, float* ws) {
    const int b = threadIdx.x >> 6;
    const int lane = threadIdx.x & 63;
    __shared__ float ln_s[NB][NCH];

    float se = ws[O_SUME + b];
    float ctx = (lane < NCH) ? (ws[O_CTX + b * NCH + lane] / se) : 0.f;
    float v = ctx, v2 = ctx * ctx;
#pragma unroll
    for (int m = 16; m; m >>= 1) {
        v  += __shfl_xor(v, m, 64);
        v2 += __shfl_xor(v2, m, 64);
    }
    float mu = v / (float)NCH;
    float var = v2 / (float)NCH - mu * mu;
    float lnv = (ctx - mu) * rsqrtf(var + 1e-5f);
    if (lane < NCH) ln_s[b][lane] = lnv;
    __syncthreads();

    float s = 0.f;
#pragma unroll
    for (int ch = 0; ch < NCH; ++ch) s = fmaf(wup[lane * NCH + ch], ln_s[b][ch], s);
    float sa = fminf(fmaxf((s + 3.f) * (1.f / 6.f), 0.f), 1.f);
    ws[O_SA + b * NC + lane] = sa;

    if (lane < NCH) {
        float l = ws[O_QL + b * NCH + lane] * (1.f / (float)NPIX);
        float mx = l;
#pragma unroll
        for (int m = 16; m; m >>= 1) mx = fmaxf(mx, __shfl_xor(mx, m, 64));
        float e = __expf(l - mx);
        float sm = e;
#pragma unroll
        for (int m = 16; m; m >>= 1) sm += __shfl_xor(sm, m, 64);
        ws[O_AVGX + b * NCH + lane] = e / sm;
    }
}

// ---------------- Pass 3: S_ca = sum_n sigmoid(avg_x . relu(wvl x)) ----------------
__global__ __launch_bounds__(256) void k_pass3(
    const float* __restrict__ x, float* ws) {
    const int b = blockIdx.y;
    const float* xb = x + (size_t)b * NC * NPIX;
    const float* wt = ws + O_WT3;
    __shared__ float red;
    if (threadIdx.x == 0) red = 0.f;
    __syncthreads();

    const int n = blockIdx.x * 256 + threadIdx.x;
    float dv[NCH];
#pragma unroll
    for (int i = 0; i < NCH; ++i) dv[i] = 0.f;
    for (int c = 0; c < NC; ++c) {
        const float xv = xb[(size_t)c * NPIX + n];
        const float* wr = wt + c * NCH;
#pragma unroll
        for (int ch = 0; ch < NCH; ++ch) dv[ch] = fmaf(wr[ch], xv, dv[ch]);
    }
    float s = 0.f;
#pragma unroll
    for (int ch = 0; ch < NCH; ++ch)
        s = fmaf(ws[O_AVGX + b * NCH + ch], fmaxf(dv[ch], 0.f), s);
    float acc = wave_sum64(1.f / (1.f + __expf(-s)));
    if ((threadIdx.x & 63) == 0) atomicAdd(&red, acc);
    __syncthreads();
    if (threadIdx.x == 0) atomicAdd(&ws[O_SCA + b], red);
}

// ---------------- Pass 4: SK gating -> K[b,c] ----------------
__global__ __launch_bounds__(256) void k_pass4(
    const float* __restrict__ wsk1, const float* __restrict__ wsk2,
    float* ws) {
    const int b = threadIdx.x >> 6;
    const int lane = threadIdx.x & 63;
    __shared__ float u_s[NB][NC];
    __shared__ float a1_s[NB][NCH];

    float sca = ws[O_SCA + b];
    float sa = ws[O_SA + b * NC + lane];
    float invn = 1.f / (float)NPIX;
    u_s[b][lane] = fmaf(sa, sca * invn, invn);
    __syncthreads();
    if (lane < NCH) {
        float s = 0.f;
#pragma unroll
        for (int c = 0; c < NC; ++c) s = fmaf(wsk1[lane * NC + c], u_s[b][c], s);
        a1_s[b][lane] = fmaxf(s, 0.f);
    }
    __syncthreads();
    float s2 = 0.f;
#pragma unroll
    for (int ch = 0; ch < NCH; ++ch) s2 = fmaf(wsk2[lane * NCH + ch], a1_s[b][ch], s2);
    s2 = fmaxf(s2, 0.f);
    float mx = s2;
#pragma unroll
    for (int m = 32; m; m >>= 1) mx = fmaxf(mx, __shfl_xor(mx, m, 64));
    float e = __expf(s2 - mx);
    float sm = e;
#pragma unroll
    for (int m = 32; m; m >>= 1) sm += __shfl_xor(sm, m, 64);
    float a = e / sm;
    ws[O_K + b * NC + lane] = fmaf(a, sa * sca, 1.f - a);
}

// ---------------- Pass 5: out = K[b,c] + relu(wres x) ----------------
__global__ __launch_bounds__(256) void k_pass5(
    const float* __restrict__ x, const float* ws, float* __restrict__ out) {
    const int b = blockIdx.y;
    const float* xb = x + (size_t)b * NC * NPIX;
    const float* wt = ws + O_WT5;
    float* ob = out + (size_t)b * NC * NPIX;
    const int n = blockIdx.x * 256 + threadIdx.x;

    float acc[NC];
#pragma unroll
    for (int o = 0; o < NC; ++o) acc[o] = 0.f;
    for (int c = 0; c < NC; ++c) {
        const float xv = xb[(size_t)c * NPIX + n];
        const float* wr = wt + c * NC;
#pragma unroll
        for (int o = 0; o < NC; ++o) acc[o] = fmaf(wr[o], xv, acc[o]);
    }
#pragma unroll
    for (int o = 0; o < NC; ++o)
        ob[(size_t)o * NPIX + n] = ws[O_K + b * NC + o] + fmaxf(acc[o], 0.f);
}

extern "C" void kernel_launch(void* const* d_in, const int* in_sizes, int n_in,
                              void* d_out, int out_size, void* d_ws, size_t ws_size,
                              hipStream_t stream) {
    const float* x    = (const float*)d_in[0];
    const float* wqr  = (const float*)d_in[1];
    const float* wvr  = (const float*)d_in[2];
    const float* wup  = (const float*)d_in[3];
    const float* wql  = (const float*)d_in[4];
    const float* wvl  = (const float*)d_in[5];
    const float* wsk1 = (const float*)d_in[6];
    const float* wsk2 = (const float*)d_in[7];
    const float* wres = (const float*)d_in[8];
    float* out = (float*)d_out;
    float* ws  = (float*)d_ws;

    // zero the accumulator region
    hipMemsetAsync(d_ws, 0, 272 * sizeof(float), stream);

    dim3 blk(256);
    k_prep<<<dim3(1), blk, 0, stream>>>(wqr, wvr, wql, wvl, wres, ws);
    dim3 g(NPIX / 256, NB);          // 512 x 4 = 2048 blocks
    k_pass1<<<g, blk, 0, stream>>>(x, ws);
    k_pass2<<<dim3(1), blk, 0, stream>>>(wup, ws);
    k_pass3<<<g, blk, 0, stream>>>(x, ws);
    k_pass4<<<dim3(1), blk, 0, stream>>>(wsk1, wsk2, ws);
    k_pass5<<<g, blk, 0, stream>>>(x, ws, out);
}